// Round 17
// baseline (281.105 us; speedup 1.0000x reference)
//
#include <hip/hip_runtime.h>
#include <cstdint>
#include <cstddef>

typedef __attribute__((ext_vector_type(8))) short short8v;   // 8 bf16 / 4 VGPRs
typedef __attribute__((ext_vector_type(4))) float f32x4;

#define BSHIFT 9            // 512 nodes per bucket
#define NBUCK_MAX 256
#define BCAP 16384          // fixed bucket capacity (mean 8192, sigma ~90)
#define F8SCALE 16.0f
#define F8INV   0.0625f

__device__ __forceinline__ unsigned short f2bf_rne(float x) {
    unsigned int u = __float_as_uint(x);
    return (unsigned short)((u + 0x7fffu + ((u >> 16) & 1u)) >> 16);
}

// pack 8 f32 (two float4) -> 8 bf16 via HW v_cvt_pk_bf16_f32 (RNE)
__device__ __forceinline__ short8v pack_bf16x8(float4 a, float4 b) {
    unsigned int u0, u1, u2, u3;
    asm("v_cvt_pk_bf16_f32 %0, %1, %2" : "=v"(u0) : "v"(a.x), "v"(a.y));
    asm("v_cvt_pk_bf16_f32 %0, %1, %2" : "=v"(u1) : "v"(a.z), "v"(a.w));
    asm("v_cvt_pk_bf16_f32 %0, %1, %2" : "=v"(u2) : "v"(b.x), "v"(b.y));
    asm("v_cvt_pk_bf16_f32 %0, %1, %2" : "=v"(u3) : "v"(b.z), "v"(b.w));
    uint4 r = make_uint4(u0, u1, u2, u3);
    return *(short8v*)&r;
}

// fp8 e4m3 (OCP) HW converts
__device__ __forceinline__ unsigned int pk_fp8(float a, float b, float c, float d) {
    int r = 0;
    r = __builtin_amdgcn_cvt_pk_fp8_f32(a, b, r, false);   // bytes 0,1
    r = __builtin_amdgcn_cvt_pk_fp8_f32(c, d, r, true);    // bytes 2,3
    return (unsigned int)r;
}
__device__ __forceinline__ void accf8(float* a, uint2 v) {
    auto p0 = __builtin_amdgcn_cvt_pk_f32_fp8((int)v.x, false);
    auto p1 = __builtin_amdgcn_cvt_pk_f32_fp8((int)v.x, true);
    auto p2 = __builtin_amdgcn_cvt_pk_f32_fp8((int)v.y, false);
    auto p3 = __builtin_amdgcn_cvt_pk_f32_fp8((int)v.y, true);
    a[0] += p0[0]; a[1] += p0[1];
    a[2] += p1[0]; a[3] += p1[1];
    a[4] += p2[0]; a[5] += p2[1];
    a[6] += p3[0]; a[7] += p3[1];
}

// ---------------- weight prep (+ bcur init) ----------------
// B1h: permuted [mfma_col][K=256] (col c -> channel (c&15)*8 + (c>>4)) for gemm1.
// B2t: NATURAL [och][K=128] bf16 of [Wmu|Wls] (och 0..63 mu, 64..127 ls) for fused prop2z.

__global__ __launch_bounds__(256) void k_prepB(const float* __restrict__ W1,
                                               const float* __restrict__ Wmu,
                                               const float* __restrict__ Wls,
                                               unsigned short* __restrict__ B1h,
                                               unsigned short* __restrict__ B2t,
                                               int* __restrict__ bcur) {
    int i = blockIdx.x * 256 + threadIdx.x;
    if (blockIdx.x == 0 && threadIdx.x < NBUCK_MAX) bcur[threadIdx.x] = 0;
    if (i < 256 * 128) {               // W1 [256][128]
        int k = i >> 7, c = i & 127;
        int ch = ((c & 15) << 3) | (c >> 4);
        B1h[c * 256 + k] = f2bf_rne(W1[k * 128 + ch]);
    }
    if (i < 128 * 128) {               // [Wmu|Wls] -> natural transpose
        int k = i >> 7, och = i & 127;
        float vv = (och < 64) ? Wmu[k * 64 + och] : Wls[k * 64 + (och - 64)];
        B2t[och * 128 + k] = f2bf_rne(vv);
    }
}

// ---------------- CSR build: fixed-capacity bucketed (512 nodes/bucket) ----------------

// packed edge: (src << 9) | (dst & 511)
__global__ __launch_bounds__(256) void k_scatb(const int* __restrict__ srcv,
                                               const int* __restrict__ dstv,
                                               int* __restrict__ bcur,
                                               unsigned int* __restrict__ ebuf, int E) {
    __shared__ int hcnt[NBUCK_MAX], hbase[NBUCK_MAX], hcur[NBUCK_MAX];
    int t = threadIdx.x;
    for (int b = t; b < NBUCK_MAX; b += 256) { hcnt[b] = 0; hcur[b] = 0; }
    __syncthreads();
    int base = blockIdx.x * 4096;
    for (int q = 0; q < 16; ++q) {
        int i = base + q * 256 + t;
        if (i < E) atomicAdd(&hcnt[dstv[i] >> BSHIFT], 1);
    }
    __syncthreads();
    for (int b = t; b < NBUCK_MAX; b += 256)
        hbase[b] = hcnt[b] ? atomicAdd(&bcur[b], hcnt[b]) : 0;
    __syncthreads();
    for (int q = 0; q < 16; ++q) {
        int i = base + q * 256 + t;
        if (i < E) {
            int d = dstv[i], b = d >> BSHIFT;
            int off = hbase[b] + atomicAdd(&hcur[b], 1);
            if (off < BCAP)   // overflow guard (P ~ 0 for uniform dst)
                ebuf[(size_t)b * BCAP + off] = ((unsigned)srcv[i] << 9) | (unsigned)(d & 511);
        }
    }
}

// per-bucket counting sort -> colv (padded layout), rowstart/rowend, dinv
__global__ __launch_bounds__(512) void k_bsort(const unsigned int* __restrict__ ebuf,
                                               const int* __restrict__ bcur,
                                               int* __restrict__ colv,
                                               int* __restrict__ rowstart,
                                               int* __restrict__ rowend,
                                               float* __restrict__ dinv, int n) {
    __shared__ int cnt[512], sc[512], cur[512];
    int t = threadIdx.x;
    int b = blockIdx.x;
    int node0 = b << BSHIFT;
    int nn = min(512, n - node0);
    int s0 = (int)((size_t)b * BCAP);
    int total = min(bcur[b], BCAP);
    cnt[t] = 0;
    __syncthreads();
    for (int i = t; i < total; i += 512)
        atomicAdd(&cnt[ebuf[s0 + i] & 511u], 1);
    __syncthreads();
    int v = cnt[t];
    sc[t] = v;
    __syncthreads();
    for (int off = 1; off < 512; off <<= 1) {
        int x = 0;
        if (t >= off) x = sc[t - off];
        __syncthreads();
        if (t >= off) sc[t] += x;
        __syncthreads();
    }
    if (t < nn) {
        int rs = s0 + sc[t] - v;
        cur[t] = rs;
        rowstart[node0 + t] = rs;
        rowend[node0 + t] = rs + v;
        dinv[node0 + t] = rsqrtf((float)(v + 1));   // +1 self-loop
    }
    __syncthreads();
    for (int i = t; i < total; i += 512) {
        unsigned int pv = ebuf[s0 + i];
        int pos = atomicAdd(&cur[pv & 511u], 1);
        colv[pos] = (int)(pv >> 9);
    }
}

// ---------------- GEMM1: h' = fp8( F8SCALE * dinv .* (x @ W1) ) ----------------
// 16-row waves (4 waves x 16 = 64 rows/block). A row fully preloaded per lane;
// B-hi staged in LDS in two 32KB K-halves. A f32->bf16 via v_cvt_pk_bf16_f32.

__global__ __launch_bounds__(256) void k_gemm1(const float* __restrict__ A,
                                               const unsigned short* __restrict__ Bth,
                                               const float* __restrict__ dinv,
                                               unsigned char* __restrict__ Cf8, int M) {
    const int K = 256;
    __shared__ unsigned short Bs[128 * 128];   // 32 KB: one K-half
    const int tid = threadIdx.x;
    const int w = tid >> 6, l = tid & 63;
    const int lr = l & 15, lq = l >> 4;
    const int row0 = blockIdx.x * 64 + w * 16;

    int rg = row0 + lr;
    const float* ap = A + (size_t)(rg < M ? rg : 0) * K + lq * 8;

    float4 ar[8][2];
#pragma unroll
    for (int s = 0; s < 8; ++s) {
        ar[s][0] = *(const float4*)(ap + s * 32);
        ar[s][1] = *(const float4*)(ap + s * 32 + 4);
    }

    f32x4 acc[8];
#pragma unroll
    for (int ct = 0; ct < 8; ++ct) acc[ct] = (f32x4){0.f, 0.f, 0.f, 0.f};

#pragma unroll
    for (int h = 0; h < 2; ++h) {
        if (h) __syncthreads();
#pragma unroll
        for (int r = 0; r < 8; ++r) {
            int rw = r * 4 + w;
            int sl = rw >> 3, ct = rw & 7;
            short8v v = *(const short8v*)(Bth + (size_t)(ct * 16 + lr) * K + (h * 4 + sl) * 32 + lq * 8);
            *(short8v*)(&Bs[(rw * 64 + l) * 8]) = v;
        }
        __syncthreads();

#pragma unroll
        for (int sl = 0; sl < 4; ++sl) {
            int sg = h * 4 + sl;
            short8v ah = pack_bf16x8(ar[sg][0], ar[sg][1]);
#pragma unroll
            for (int ct = 0; ct < 8; ++ct) {
                short8v bh = *(const short8v*)(&Bs[((sl * 8 + ct) * 64 + l) * 8]);
                acc[ct] = __builtin_amdgcn_mfma_f32_16x16x32_bf16(ah, bh, acc[ct], 0, 0, 0);
            }
        }
    }

    int rbase = row0 + (lq << 2);
#pragma unroll
    for (int j = 0; j < 4; ++j) {
        int row = rbase + j;
        if (row < M) {
            float dv = dinv[row] * F8SCALE;
            uint2 r;
            r.x = pk_fp8(dv * acc[0][j], dv * acc[1][j], dv * acc[2][j], dv * acc[3][j]);
            r.y = pk_fp8(dv * acc[4][j], dv * acc[5][j], dv * acc[6][j], dv * acc[7][j]);
            *(uint2*)(Cf8 + (size_t)row * 128 + lr * 8) = r;
        }
    }
}

// ---------------- prop1: hidden' = fp8( F8SCALE * dinv .* relu(dinv_v*agg + b1) ) ----------------
// 4 nodes/wave, 16 lanes x 8B (fp8 row = 128B = 2 lines); unroll 4.

__global__ __launch_bounds__(256) void k_prop1(const unsigned char* __restrict__ hf,
                                               const int* __restrict__ colv,
                                               const int* __restrict__ rowstart,
                                               const int* __restrict__ rowend,
                                               const float* __restrict__ dinv,
                                               const float* __restrict__ bias,
                                               unsigned char* __restrict__ of, int n) {
    int wid = (blockIdx.x * 256 + threadIdx.x) >> 6;
    int nid = wid * 4 + ((threadIdx.x >> 4) & 3);
    if (nid >= n) return;
    int cl = threadIdx.x & 15;
    const unsigned char* hp = hf + cl * 8;
    int s = rowstart[nid], e = rowend[nid];
    float a[8] = {0.f, 0.f, 0.f, 0.f, 0.f, 0.f, 0.f, 0.f};
    int i = s;
    for (; i + 4 <= e; i += 4) {
        int c0 = colv[i], c1 = colv[i + 1], c2 = colv[i + 2], c3 = colv[i + 3];
        uint2 v0 = *(const uint2*)(hp + (size_t)c0 * 128);
        uint2 v1 = *(const uint2*)(hp + (size_t)c1 * 128);
        uint2 v2 = *(const uint2*)(hp + (size_t)c2 * 128);
        uint2 v3 = *(const uint2*)(hp + (size_t)c3 * 128);
        accf8(a, v0); accf8(a, v1); accf8(a, v2); accf8(a, v3);
    }
    for (; i < e; ++i) {
        int c = colv[i];
        uint2 v = *(const uint2*)(hp + (size_t)c * 128);
        accf8(a, v);
    }
    uint2 vo = *(const uint2*)(hp + (size_t)nid * 128);   // self-loop
    accf8(a, vo);
    float dv = dinv[nid];
    float din = dv * F8INV;          // undo x16 input scale
    float dos = dv * F8SCALE;        // re-apply for fp8 output (+ fold next-layer dinv)
    float4 b0 = *(const float4*)(bias + cl * 8);
    float4 b1v = *(const float4*)(bias + cl * 8 + 4);
    float bb[8] = {b0.x, b0.y, b0.z, b0.w, b1v.x, b1v.y, b1v.z, b1v.w};
    float o[8];
#pragma unroll
    for (int k = 0; k < 8; ++k)
        o[k] = fmaxf(a[k] * din + bb[k], 0.f) * dos;
    uint2 r;
    r.x = pk_fp8(o[0], o[1], o[2], o[3]);
    r.y = pk_fp8(o[4], o[5], o[6], o[7]);
    *(uint2*)(of + (size_t)nid * 128 + cl * 8) = r;
}

// ---------------- fused prop2 + GEMM2 + epilogue (INDEPENDENT WAVES, no barriers) ----------------
// Block = 16 nodes, 4 waves; wave w owns 4 nodes end-to-end (proven gather shape, grid n/16).
// Phase 1: single 4-node/wave gather -> wave-private LDS slice aggb[w][4][136] (bf16).
//          Intra-wave s_waitcnt lgkmcnt(0) + sched_barrier only — NO __syncthreads.
// Phase 2: wave computes all 8 och-tiles: D = agg(4x128 valid rows) @ B2t tiles (L2-hot).
//          A row index clamped (lr&3): garbage only pollutes discarded D rows 4..15.
//          mu = tile t, ls = tile t+4 in the SAME lane -> zero-shuffle reparam.

__global__ __launch_bounds__(256) void k_prop2z(const unsigned char* __restrict__ hf,
                                                const int* __restrict__ colv,
                                                const int* __restrict__ rowstart,
                                                const int* __restrict__ rowend,
                                                const float* __restrict__ dinv,
                                                const unsigned short* __restrict__ B2t,
                                                const float* __restrict__ bmu,
                                                const float* __restrict__ bls,
                                                const float* __restrict__ eps,
                                                float* __restrict__ zout,
                                                float* __restrict__ muout,
                                                float* __restrict__ lsout, int n) {
    __shared__ unsigned short aggb[4][4][136];   // 4.25 KB, wave-private slices
    const int tid = threadIdx.x;
    const int w = tid >> 6, l = tid & 63;
    const int wbase = blockIdx.x * 16 + w * 4;   // 4 nodes per wave

    // ---- phase 1: 4-node/wave gather (proven shape) ----
    {
        const int g = l >> 4, cl = l & 15;
        int nid = wbase + g;
        float a[8] = {0.f, 0.f, 0.f, 0.f, 0.f, 0.f, 0.f, 0.f};
        float dv = 0.f;
        if (nid < n) {
            const unsigned char* hp = hf + cl * 8;
            int s = rowstart[nid], e = rowend[nid];
            int i = s;
            for (; i + 4 <= e; i += 4) {
                int c0 = colv[i], c1 = colv[i + 1], c2 = colv[i + 2], c3 = colv[i + 3];
                uint2 v0 = *(const uint2*)(hp + (size_t)c0 * 128);
                uint2 v1 = *(const uint2*)(hp + (size_t)c1 * 128);
                uint2 v2 = *(const uint2*)(hp + (size_t)c2 * 128);
                uint2 v3 = *(const uint2*)(hp + (size_t)c3 * 128);
                accf8(a, v0); accf8(a, v1); accf8(a, v2); accf8(a, v3);
            }
            for (; i < e; ++i) {
                int c = colv[i];
                uint2 v = *(const uint2*)(hp + (size_t)c * 128);
                accf8(a, v);
            }
            uint2 vo = *(const uint2*)(hp + (size_t)nid * 128);   // self-loop
            accf8(a, vo);
            dv = dinv[nid] * F8INV;
        }
        short8v r;
#pragma unroll
        for (int k = 0; k < 8; ++k) r[k] = (short)f2bf_rne(a[k] * dv);
        *(short8v*)(&aggb[w][g][cl * 8]) = r;
    }
    // intra-wave LDS drain; no block barrier (waves are independent)
    asm volatile("s_waitcnt lgkmcnt(0)" ::: "memory");
    __builtin_amdgcn_sched_barrier(0);

    // ---- phase 2: all 8 och-tiles in this wave ----
    const int lr = l & 15, lq = l >> 4;
    f32x4 accD[8];
#pragma unroll
    for (int t = 0; t < 8; ++t) accD[t] = (f32x4){0.f, 0.f, 0.f, 0.f};
#pragma unroll
    for (int sl = 0; sl < 4; ++sl) {
        // A row clamped to valid slice; rows 4..15 of D are discarded anyway
        short8v af = *(const short8v*)(&aggb[w][lr & 3][sl * 32 + lq * 8]);
#pragma unroll
        for (int t = 0; t < 8; ++t) {
            short8v bt = *(const short8v*)(B2t + (size_t)(t * 16 + lr) * 128 + sl * 32 + lq * 8);
            accD[t] = __builtin_amdgcn_mfma_f32_16x16x32_bf16(af, bt, accD[t], 0, 0, 0);
        }
    }

    // ---- epilogue: D rows 0..3 (lq==0) are the 4 nodes; mu = tile t, ls = tile t+4 ----
    if (lq == 0) {
#pragma unroll
        for (int t = 0; t < 4; ++t) {
            int och = t * 16 + lr;
            float bmv = bmu[och], blv = bls[och];
#pragma unroll
            for (int j = 0; j < 4; ++j) {
                int nid = wbase + j;
                if (nid < n) {
                    float mu = accD[t][j] + bmv;
                    float ls = accD[t + 4][j] + blv;
                    size_t o = (size_t)nid * 64 + och;
                    float z = mu + eps[o] * __expf(ls);
                    zout[o] = z;
                    muout[o] = mu;
                    lsout[o] = ls;
                }
            }
        }
    }
}

// ---------------- launch ----------------

extern "C" void kernel_launch(void* const* d_in, const int* in_sizes, int n_in,
                              void* d_out, int out_size, void* d_ws, size_t ws_size,
                              hipStream_t stream) {
    const float* x   = (const float*)d_in[0];
    const int*   ei  = (const int*)d_in[1];
    const float* W1  = (const float*)d_in[2];
    const float* b1  = (const float*)d_in[3];
    const float* Wmu = (const float*)d_in[4];
    const float* bmu = (const float*)d_in[5];
    const float* Wls = (const float*)d_in[6];
    const float* bls = (const float*)d_in[7];
    const float* eps = (const float*)d_in[8];

    const int n = in_sizes[0] / 256;   // 100000
    const int E = in_sizes[1] / 2;     // 1600000
    const int* srcv = ei;
    const int* dstv = ei + E;
    const int nbuck = (n + 511) >> BSHIFT;

    char* w = (char*)d_ws;
    auto alloc = [&](size_t bytes) -> char* {
        char* p = w;
        w += (bytes + 255) & ~(size_t)255;
        return p;
    };
    float* dinv     = (float*)alloc((size_t)n * 4);
    int*   rowstart = (int*)alloc((size_t)n * 4);
    int*   rowend   = (int*)alloc((size_t)n * 4);
    int*   bcur     = (int*)alloc((size_t)NBUCK_MAX * 4);
    unsigned int* ebuf = (unsigned int*)alloc((size_t)nbuck * BCAP * 4);
    int*   colv     = (int*)alloc((size_t)nbuck * BCAP * 4);
    unsigned short* B1h = (unsigned short*)alloc(128 * 256 * 2);
    unsigned short* B2t = (unsigned short*)alloc(128 * 128 * 2);
    unsigned char* hf8   = (unsigned char*)alloc((size_t)n * 128);   // h' fp8
    unsigned char* hidf8 = (unsigned char*)alloc((size_t)n * 128);   // hidden' fp8

    const int ecb = (E + 4095) / 4096;

    k_prepB<<<128, 256, 0, stream>>>(W1, Wmu, Wls, B1h, B2t, bcur);
    k_scatb<<<ecb, 256, 0, stream>>>(srcv, dstv, bcur, ebuf, E);
    k_bsort<<<nbuck, 512, 0, stream>>>(ebuf, bcur, colv, rowstart, rowend, dinv, n);

    k_gemm1<<<(n + 63) / 64, 256, 0, stream>>>(x, B1h, dinv, hf8, n);
    k_prop1<<<(n + 15) / 16, 256, 0, stream>>>(hf8, colv, rowstart, rowend, dinv, b1, hidf8, n);

    float* zout  = (float*)d_out;
    float* muout = zout + (size_t)n * 64;
    float* lsout = muout + (size_t)n * 64;
    k_prop2z<<<(n + 15) / 16, 256, 0, stream>>>(hidf8, colv, rowstart, rowend, dinv,
                                                B2t, bmu, bls, eps,
                                                zout, muout, lsout, n);
}

// Round 18
// 223.948 us; speedup vs baseline: 1.2552x; 1.2552x over previous
//
#include <hip/hip_runtime.h>
#include <cstdint>
#include <cstddef>

typedef __attribute__((ext_vector_type(8))) short short8v;   // 8 bf16 / 4 VGPRs
typedef __attribute__((ext_vector_type(4))) float f32x4;

#define BSHIFT 9            // 512 nodes per bucket
#define NBUCK_MAX 256
#define BCAP 16384          // fixed bucket capacity (mean 8192, sigma ~90)
#define F8SCALE 16.0f
#define F8INV   0.0625f

__device__ __forceinline__ unsigned short f2bf_rne(float x) {
    unsigned int u = __float_as_uint(x);
    return (unsigned short)((u + 0x7fffu + ((u >> 16) & 1u)) >> 16);
}

// pack 8 f32 (two float4) -> 8 bf16 via HW v_cvt_pk_bf16_f32 (RNE)
__device__ __forceinline__ short8v pack_bf16x8(float4 a, float4 b) {
    unsigned int u0, u1, u2, u3;
    asm("v_cvt_pk_bf16_f32 %0, %1, %2" : "=v"(u0) : "v"(a.x), "v"(a.y));
    asm("v_cvt_pk_bf16_f32 %0, %1, %2" : "=v"(u1) : "v"(a.z), "v"(a.w));
    asm("v_cvt_pk_bf16_f32 %0, %1, %2" : "=v"(u2) : "v"(b.x), "v"(b.y));
    asm("v_cvt_pk_bf16_f32 %0, %1, %2" : "=v"(u3) : "v"(b.z), "v"(b.w));
    uint4 r = make_uint4(u0, u1, u2, u3);
    return *(short8v*)&r;
}

// fp8 e4m3 (OCP) HW converts
__device__ __forceinline__ unsigned int pk_fp8(float a, float b, float c, float d) {
    int r = 0;
    r = __builtin_amdgcn_cvt_pk_fp8_f32(a, b, r, false);   // bytes 0,1
    r = __builtin_amdgcn_cvt_pk_fp8_f32(c, d, r, true);    // bytes 2,3
    return (unsigned int)r;
}
__device__ __forceinline__ void accf8(float* a, uint2 v) {
    auto p0 = __builtin_amdgcn_cvt_pk_f32_fp8((int)v.x, false);
    auto p1 = __builtin_amdgcn_cvt_pk_f32_fp8((int)v.x, true);
    auto p2 = __builtin_amdgcn_cvt_pk_f32_fp8((int)v.y, false);
    auto p3 = __builtin_amdgcn_cvt_pk_f32_fp8((int)v.y, true);
    a[0] += p0[0]; a[1] += p0[1];
    a[2] += p1[0]; a[3] += p1[1];
    a[4] += p2[0]; a[5] += p2[1];
    a[6] += p3[0]; a[7] += p3[1];
}

// ---------------- weight prep (+ bcur init) ----------------
// B1h: permuted [mfma_col][K=256] (col c -> channel (c&15)*8 + (c>>4)) for gemm1.
// B2t: NATURAL [och][K=128] bf16 of [Wmu|Wls] (och 0..63 mu, 64..127 ls) for fused prop2z.

__global__ __launch_bounds__(256) void k_prepB(const float* __restrict__ W1,
                                               const float* __restrict__ Wmu,
                                               const float* __restrict__ Wls,
                                               unsigned short* __restrict__ B1h,
                                               unsigned short* __restrict__ B2t,
                                               int* __restrict__ bcur) {
    int i = blockIdx.x * 256 + threadIdx.x;
    if (blockIdx.x == 0 && threadIdx.x < NBUCK_MAX) bcur[threadIdx.x] = 0;
    if (i < 256 * 128) {               // W1 [256][128]
        int k = i >> 7, c = i & 127;
        int ch = ((c & 15) << 3) | (c >> 4);
        B1h[c * 256 + k] = f2bf_rne(W1[k * 128 + ch]);
    }
    if (i < 128 * 128) {               // [Wmu|Wls] -> natural transpose
        int k = i >> 7, och = i & 127;
        float vv = (och < 64) ? Wmu[k * 64 + och] : Wls[k * 64 + (och - 64)];
        B2t[och * 128 + k] = f2bf_rne(vv);
    }
}

// ---------------- CSR build: fixed-capacity bucketed (512 nodes/bucket) ----------------

// packed edge: (src << 9) | (dst & 511)
__global__ __launch_bounds__(256) void k_scatb(const int* __restrict__ srcv,
                                               const int* __restrict__ dstv,
                                               int* __restrict__ bcur,
                                               unsigned int* __restrict__ ebuf, int E) {
    __shared__ int hcnt[NBUCK_MAX], hbase[NBUCK_MAX], hcur[NBUCK_MAX];
    int t = threadIdx.x;
    for (int b = t; b < NBUCK_MAX; b += 256) { hcnt[b] = 0; hcur[b] = 0; }
    __syncthreads();
    int base = blockIdx.x * 4096;
    for (int q = 0; q < 16; ++q) {
        int i = base + q * 256 + t;
        if (i < E) atomicAdd(&hcnt[dstv[i] >> BSHIFT], 1);
    }
    __syncthreads();
    for (int b = t; b < NBUCK_MAX; b += 256)
        hbase[b] = hcnt[b] ? atomicAdd(&bcur[b], hcnt[b]) : 0;
    __syncthreads();
    for (int q = 0; q < 16; ++q) {
        int i = base + q * 256 + t;
        if (i < E) {
            int d = dstv[i], b = d >> BSHIFT;
            int off = hbase[b] + atomicAdd(&hcur[b], 1);
            if (off < BCAP)   // overflow guard (P ~ 0 for uniform dst)
                ebuf[(size_t)b * BCAP + off] = ((unsigned)srcv[i] << 9) | (unsigned)(d & 511);
        }
    }
}

// per-bucket counting sort -> colv (padded layout), rowstart/rowend, dinv
__global__ __launch_bounds__(512) void k_bsort(const unsigned int* __restrict__ ebuf,
                                               const int* __restrict__ bcur,
                                               int* __restrict__ colv,
                                               int* __restrict__ rowstart,
                                               int* __restrict__ rowend,
                                               float* __restrict__ dinv, int n) {
    __shared__ int cnt[512], sc[512], cur[512];
    int t = threadIdx.x;
    int b = blockIdx.x;
    int node0 = b << BSHIFT;
    int nn = min(512, n - node0);
    int s0 = (int)((size_t)b * BCAP);
    int total = min(bcur[b], BCAP);
    cnt[t] = 0;
    __syncthreads();
    for (int i = t; i < total; i += 512)
        atomicAdd(&cnt[ebuf[s0 + i] & 511u], 1);
    __syncthreads();
    int v = cnt[t];
    sc[t] = v;
    __syncthreads();
    for (int off = 1; off < 512; off <<= 1) {
        int x = 0;
        if (t >= off) x = sc[t - off];
        __syncthreads();
        if (t >= off) sc[t] += x;
        __syncthreads();
    }
    if (t < nn) {
        int rs = s0 + sc[t] - v;
        cur[t] = rs;
        rowstart[node0 + t] = rs;
        rowend[node0 + t] = rs + v;
        dinv[node0 + t] = rsqrtf((float)(v + 1));   // +1 self-loop
    }
    __syncthreads();
    for (int i = t; i < total; i += 512) {
        unsigned int pv = ebuf[s0 + i];
        int pos = atomicAdd(&cur[pv & 511u], 1);
        colv[pos] = (int)(pv >> 9);
    }
}

// ---------------- GEMM1: h' = fp8( F8SCALE * dinv .* (x @ W1) ) ----------------
// 16-row waves (4 waves x 16 = 64 rows/block). A row fully preloaded per lane;
// B-hi staged in LDS in two 32KB K-halves. A f32->bf16 via v_cvt_pk_bf16_f32.

__global__ __launch_bounds__(256) void k_gemm1(const float* __restrict__ A,
                                               const unsigned short* __restrict__ Bth,
                                               const float* __restrict__ dinv,
                                               unsigned char* __restrict__ Cf8, int M) {
    const int K = 256;
    __shared__ unsigned short Bs[128 * 128];   // 32 KB: one K-half
    const int tid = threadIdx.x;
    const int w = tid >> 6, l = tid & 63;
    const int lr = l & 15, lq = l >> 4;
    const int row0 = blockIdx.x * 64 + w * 16;

    int rg = row0 + lr;
    const float* ap = A + (size_t)(rg < M ? rg : 0) * K + lq * 8;

    float4 ar[8][2];
#pragma unroll
    for (int s = 0; s < 8; ++s) {
        ar[s][0] = *(const float4*)(ap + s * 32);
        ar[s][1] = *(const float4*)(ap + s * 32 + 4);
    }

    f32x4 acc[8];
#pragma unroll
    for (int ct = 0; ct < 8; ++ct) acc[ct] = (f32x4){0.f, 0.f, 0.f, 0.f};

#pragma unroll
    for (int h = 0; h < 2; ++h) {
        if (h) __syncthreads();
#pragma unroll
        for (int r = 0; r < 8; ++r) {
            int rw = r * 4 + w;
            int sl = rw >> 3, ct = rw & 7;
            short8v v = *(const short8v*)(Bth + (size_t)(ct * 16 + lr) * K + (h * 4 + sl) * 32 + lq * 8);
            *(short8v*)(&Bs[(rw * 64 + l) * 8]) = v;
        }
        __syncthreads();

#pragma unroll
        for (int sl = 0; sl < 4; ++sl) {
            int sg = h * 4 + sl;
            short8v ah = pack_bf16x8(ar[sg][0], ar[sg][1]);
#pragma unroll
            for (int ct = 0; ct < 8; ++ct) {
                short8v bh = *(const short8v*)(&Bs[((sl * 8 + ct) * 64 + l) * 8]);
                acc[ct] = __builtin_amdgcn_mfma_f32_16x16x32_bf16(ah, bh, acc[ct], 0, 0, 0);
            }
        }
    }

    int rbase = row0 + (lq << 2);
#pragma unroll
    for (int j = 0; j < 4; ++j) {
        int row = rbase + j;
        if (row < M) {
            float dv = dinv[row] * F8SCALE;
            uint2 r;
            r.x = pk_fp8(dv * acc[0][j], dv * acc[1][j], dv * acc[2][j], dv * acc[3][j]);
            r.y = pk_fp8(dv * acc[4][j], dv * acc[5][j], dv * acc[6][j], dv * acc[7][j]);
            *(uint2*)(Cf8 + (size_t)row * 128 + lr * 8) = r;
        }
    }
}

// ---------------- prop1: hidden' = fp8( F8SCALE * dinv .* relu(dinv_v*agg + b1) ) ----------------
// 4 nodes/wave, 16 lanes x 8B (fp8 row = 128B = 2 lines); unroll 4.

__global__ __launch_bounds__(256) void k_prop1(const unsigned char* __restrict__ hf,
                                               const int* __restrict__ colv,
                                               const int* __restrict__ rowstart,
                                               const int* __restrict__ rowend,
                                               const float* __restrict__ dinv,
                                               const float* __restrict__ bias,
                                               unsigned char* __restrict__ of, int n) {
    int wid = (blockIdx.x * 256 + threadIdx.x) >> 6;
    int nid = wid * 4 + ((threadIdx.x >> 4) & 3);
    if (nid >= n) return;
    int cl = threadIdx.x & 15;
    const unsigned char* hp = hf + cl * 8;
    int s = rowstart[nid], e = rowend[nid];
    float a[8] = {0.f, 0.f, 0.f, 0.f, 0.f, 0.f, 0.f, 0.f};
    int i = s;
    for (; i + 4 <= e; i += 4) {
        int c0 = colv[i], c1 = colv[i + 1], c2 = colv[i + 2], c3 = colv[i + 3];
        uint2 v0 = *(const uint2*)(hp + (size_t)c0 * 128);
        uint2 v1 = *(const uint2*)(hp + (size_t)c1 * 128);
        uint2 v2 = *(const uint2*)(hp + (size_t)c2 * 128);
        uint2 v3 = *(const uint2*)(hp + (size_t)c3 * 128);
        accf8(a, v0); accf8(a, v1); accf8(a, v2); accf8(a, v3);
    }
    for (; i < e; ++i) {
        int c = colv[i];
        uint2 v = *(const uint2*)(hp + (size_t)c * 128);
        accf8(a, v);
    }
    uint2 vo = *(const uint2*)(hp + (size_t)nid * 128);   // self-loop
    accf8(a, vo);
    float dv = dinv[nid];
    float din = dv * F8INV;          // undo x16 input scale
    float dos = dv * F8SCALE;        // re-apply for fp8 output (+ fold next-layer dinv)
    float4 b0 = *(const float4*)(bias + cl * 8);
    float4 b1v = *(const float4*)(bias + cl * 8 + 4);
    float bb[8] = {b0.x, b0.y, b0.z, b0.w, b1v.x, b1v.y, b1v.z, b1v.w};
    float o[8];
#pragma unroll
    for (int k = 0; k < 8; ++k)
        o[k] = fmaxf(a[k] * din + bb[k], 0.f) * dos;
    uint2 r;
    r.x = pk_fp8(o[0], o[1], o[2], o[3]);
    r.y = pk_fp8(o[4], o[5], o[6], o[7]);
    *(uint2*)(of + (size_t)nid * 128 + cl * 8) = r;
}

// ---------------- fused prop2 + GEMM2 + epilogue (round-11 transposed gather, fp8) ----------------
// Wave = 16 nodes, NO LDS, NO barriers. Lane l: node nl = l&15, k-chunk kc = l>>4.
// Lane accumulates channels {s4*32 + kc*8 + q} of its node -> this IS the MFMA B-frag
// layout (B[k][col=node]). D = Wtile(A, natural [och][k]) x agg(B): D col = node,
// D rows = och (kc*4+j within tile). mu = tile t, ls = tile t+4 in the SAME lane ->
// zero-shuffle reparam; 16B stores per (node, och-quad).

__global__ __launch_bounds__(256) void k_prop2z(const unsigned char* __restrict__ hf,
                                                const int* __restrict__ colv,
                                                const int* __restrict__ rowstart,
                                                const int* __restrict__ rowend,
                                                const float* __restrict__ dinv,
                                                const unsigned short* __restrict__ B2t,
                                                const float* __restrict__ bmu,
                                                const float* __restrict__ bls,
                                                const float* __restrict__ eps,
                                                float* __restrict__ zout,
                                                float* __restrict__ muout,
                                                float* __restrict__ lsout, int n) {
    const int tid = threadIdx.x;
    const int l = tid & 63;
    const int nl = l & 15;       // node lane
    const int kc = l >> 4;       // k-chunk: channels s4*32 + kc*8 .. +7
    int wid = (blockIdx.x * 256 + tid) >> 6;
    int nid = wid * 16 + nl;
    bool valid = nid < n;
    int nidc = valid ? nid : 0;

    int s = valid ? rowstart[nid] : 0;
    int e = valid ? rowend[nid] : 0;

    float a[4][8] = {{0.f}};
    const unsigned char* hp = hf + kc * 8;
    int i = s;
    for (; i + 2 <= e; i += 2) {
        int c0 = colv[i], c1 = colv[i + 1];
        uint2 v00 = *(const uint2*)(hp + (size_t)c0 * 128);
        uint2 v01 = *(const uint2*)(hp + (size_t)c0 * 128 + 32);
        uint2 v02 = *(const uint2*)(hp + (size_t)c0 * 128 + 64);
        uint2 v03 = *(const uint2*)(hp + (size_t)c0 * 128 + 96);
        uint2 v10 = *(const uint2*)(hp + (size_t)c1 * 128);
        uint2 v11 = *(const uint2*)(hp + (size_t)c1 * 128 + 32);
        uint2 v12 = *(const uint2*)(hp + (size_t)c1 * 128 + 64);
        uint2 v13 = *(const uint2*)(hp + (size_t)c1 * 128 + 96);
        accf8(a[0], v00); accf8(a[1], v01); accf8(a[2], v02); accf8(a[3], v03);
        accf8(a[0], v10); accf8(a[1], v11); accf8(a[2], v12); accf8(a[3], v13);
    }
    if (i < e) {
        int c = colv[i];
        uint2 v0 = *(const uint2*)(hp + (size_t)c * 128);
        uint2 v1 = *(const uint2*)(hp + (size_t)c * 128 + 32);
        uint2 v2 = *(const uint2*)(hp + (size_t)c * 128 + 64);
        uint2 v3 = *(const uint2*)(hp + (size_t)c * 128 + 96);
        accf8(a[0], v0); accf8(a[1], v1); accf8(a[2], v2); accf8(a[3], v3);
    }
    {   // self-loop (row nidc; dv=0 nullifies garbage for invalid lanes)
        uint2 v0 = *(const uint2*)(hp + (size_t)nidc * 128);
        uint2 v1 = *(const uint2*)(hp + (size_t)nidc * 128 + 32);
        uint2 v2 = *(const uint2*)(hp + (size_t)nidc * 128 + 64);
        uint2 v3 = *(const uint2*)(hp + (size_t)nidc * 128 + 96);
        accf8(a[0], v0); accf8(a[1], v1); accf8(a[2], v2); accf8(a[3], v3);
    }
    float dv = valid ? dinv[nid] * F8INV : 0.f;

    short8v bAgg[4];
#pragma unroll
    for (int s4 = 0; s4 < 4; ++s4)
#pragma unroll
        for (int q = 0; q < 8; ++q)
            bAgg[s4][q] = (short)f2bf_rne(a[s4][q] * dv);

    f32x4 accD[8];
#pragma unroll
    for (int t = 0; t < 8; ++t) accD[t] = (f32x4){0.f, 0.f, 0.f, 0.f};

#pragma unroll
    for (int s4 = 0; s4 < 4; ++s4) {
#pragma unroll
        for (int t = 0; t < 8; ++t) {
            short8v aW = *(const short8v*)(B2t + (size_t)(t * 16 + nl) * 128 + s4 * 32 + kc * 8);
            accD[t] = __builtin_amdgcn_mfma_f32_16x16x32_bf16(aW, bAgg[s4], accD[t], 0, 0, 0);
        }
    }

    if (valid) {
#pragma unroll
        for (int t = 0; t < 4; ++t) {
            int och0 = t * 16 + kc * 4;
            float4 bm4 = *(const float4*)(bmu + och0);
            float4 bl4 = *(const float4*)(bls + och0);
            float4 mu4, ls4, z4;
            mu4.x = accD[t][0] + bm4.x; mu4.y = accD[t][1] + bm4.y;
            mu4.z = accD[t][2] + bm4.z; mu4.w = accD[t][3] + bm4.w;
            ls4.x = accD[t + 4][0] + bl4.x; ls4.y = accD[t + 4][1] + bl4.y;
            ls4.z = accD[t + 4][2] + bl4.z; ls4.w = accD[t + 4][3] + bl4.w;
            size_t o = (size_t)nid * 64 + och0;
            float4 e4 = *(const float4*)(eps + o);
            z4.x = mu4.x + e4.x * __expf(ls4.x);
            z4.y = mu4.y + e4.y * __expf(ls4.y);
            z4.z = mu4.z + e4.z * __expf(ls4.z);
            z4.w = mu4.w + e4.w * __expf(ls4.w);
            *(float4*)(zout + o)  = z4;
            *(float4*)(muout + o) = mu4;
            *(float4*)(lsout + o) = ls4;
        }
    }
}

// ---------------- launch ----------------

extern "C" void kernel_launch(void* const* d_in, const int* in_sizes, int n_in,
                              void* d_out, int out_size, void* d_ws, size_t ws_size,
                              hipStream_t stream) {
    const float* x   = (const float*)d_in[0];
    const int*   ei  = (const int*)d_in[1];
    const float* W1  = (const float*)d_in[2];
    const float* b1  = (const float*)d_in[3];
    const float* Wmu = (const float*)d_in[4];
    const float* bmu = (const float*)d_in[5];
    const float* Wls = (const float*)d_in[6];
    const float* bls = (const float*)d_in[7];
    const float* eps = (const float*)d_in[8];

    const int n = in_sizes[0] / 256;   // 100000
    const int E = in_sizes[1] / 2;     // 1600000
    const int* srcv = ei;
    const int* dstv = ei + E;
    const int nbuck = (n + 511) >> BSHIFT;

    char* w = (char*)d_ws;
    auto alloc = [&](size_t bytes) -> char* {
        char* p = w;
        w += (bytes + 255) & ~(size_t)255;
        return p;
    };
    float* dinv     = (float*)alloc((size_t)n * 4);
    int*   rowstart = (int*)alloc((size_t)n * 4);
    int*   rowend   = (int*)alloc((size_t)n * 4);
    int*   bcur     = (int*)alloc((size_t)NBUCK_MAX * 4);
    unsigned int* ebuf = (unsigned int*)alloc((size_t)nbuck * BCAP * 4);
    int*   colv     = (int*)alloc((size_t)nbuck * BCAP * 4);
    unsigned short* B1h = (unsigned short*)alloc(128 * 256 * 2);
    unsigned short* B2t = (unsigned short*)alloc(128 * 128 * 2);
    unsigned char* hf8   = (unsigned char*)alloc((size_t)n * 128);   // h' fp8
    unsigned char* hidf8 = (unsigned char*)alloc((size_t)n * 128);   // hidden' fp8

    const int ecb = (E + 4095) / 4096;

    k_prepB<<<128, 256, 0, stream>>>(W1, Wmu, Wls, B1h, B2t, bcur);
    k_scatb<<<ecb, 256, 0, stream>>>(srcv, dstv, bcur, ebuf, E);
    k_bsort<<<nbuck, 512, 0, stream>>>(ebuf, bcur, colv, rowstart, rowend, dinv, n);

    k_gemm1<<<(n + 63) / 64, 256, 0, stream>>>(x, B1h, dinv, hf8, n);
    k_prop1<<<(n + 15) / 16, 256, 0, stream>>>(hf8, colv, rowstart, rowend, dinv, b1, hidf8, n);

    float* zout  = (float*)d_out;
    float* muout = zout + (size_t)n * 64;
    float* lsout = muout + (size_t)n * 64;
    k_prop2z<<<(n + 63) / 64, 256, 0, stream>>>(hidf8, colv, rowstart, rowend, dinv,
                                                B2t, bmu, bls, eps,
                                                zout, muout, lsout, n);
}

// Round 19
// 190.365 us; speedup vs baseline: 1.4767x; 1.1764x over previous
//
#include <hip/hip_runtime.h>
#include <cstdint>
#include <cstddef>

typedef __attribute__((ext_vector_type(8))) short short8v;   // 8 bf16 / 4 VGPRs
typedef __attribute__((ext_vector_type(4))) float f32x4;

#define BSHIFT 9            // 512 nodes per bucket
#define NBUCK_MAX 256
#define BCAP 16384          // fixed bucket capacity (mean 8192, sigma ~90)
#define F8SCALE 16.0f
#define F8INV   0.0625f

__device__ __forceinline__ unsigned short f2bf_rne(float x) {
    unsigned int u = __float_as_uint(x);
    return (unsigned short)((u + 0x7fffu + ((u >> 16) & 1u)) >> 16);
}

// pack 8 f32 (two float4) -> 8 bf16 via HW v_cvt_pk_bf16_f32 (RNE)
__device__ __forceinline__ short8v pack_bf16x8(float4 a, float4 b) {
    unsigned int u0, u1, u2, u3;
    asm("v_cvt_pk_bf16_f32 %0, %1, %2" : "=v"(u0) : "v"(a.x), "v"(a.y));
    asm("v_cvt_pk_bf16_f32 %0, %1, %2" : "=v"(u1) : "v"(a.z), "v"(a.w));
    asm("v_cvt_pk_bf16_f32 %0, %1, %2" : "=v"(u2) : "v"(b.x), "v"(b.y));
    asm("v_cvt_pk_bf16_f32 %0, %1, %2" : "=v"(u3) : "v"(b.z), "v"(b.w));
    uint4 r = make_uint4(u0, u1, u2, u3);
    return *(short8v*)&r;
}

// fp8 e4m3 (OCP) HW converts
__device__ __forceinline__ unsigned int pk_fp8(float a, float b, float c, float d) {
    int r = 0;
    r = __builtin_amdgcn_cvt_pk_fp8_f32(a, b, r, false);   // bytes 0,1
    r = __builtin_amdgcn_cvt_pk_fp8_f32(c, d, r, true);    // bytes 2,3
    return (unsigned int)r;
}
__device__ __forceinline__ void accf8(float* a, uint2 v) {
    auto p0 = __builtin_amdgcn_cvt_pk_f32_fp8((int)v.x, false);
    auto p1 = __builtin_amdgcn_cvt_pk_f32_fp8((int)v.x, true);
    auto p2 = __builtin_amdgcn_cvt_pk_f32_fp8((int)v.y, false);
    auto p3 = __builtin_amdgcn_cvt_pk_f32_fp8((int)v.y, true);
    a[0] += p0[0]; a[1] += p0[1];
    a[2] += p1[0]; a[3] += p1[1];
    a[4] += p2[0]; a[5] += p2[1];
    a[6] += p3[0]; a[7] += p3[1];
}

// ---------------- weight prep (+ bcur init) ----------------
// B1h: permuted [mfma_col][K=256] (col c -> channel (c&15)*8 + (c>>4)) for gemm1.
// B2t: NATURAL [och][K=128] bf16 of [Wmu|Wls] (och 0..63 mu, 64..127 ls) for fused prop2z.

__global__ __launch_bounds__(256) void k_prepB(const float* __restrict__ W1,
                                               const float* __restrict__ Wmu,
                                               const float* __restrict__ Wls,
                                               unsigned short* __restrict__ B1h,
                                               unsigned short* __restrict__ B2t,
                                               int* __restrict__ bcur) {
    int i = blockIdx.x * 256 + threadIdx.x;
    if (blockIdx.x == 0 && threadIdx.x < NBUCK_MAX) bcur[threadIdx.x] = 0;
    if (i < 256 * 128) {               // W1 [256][128]
        int k = i >> 7, c = i & 127;
        int ch = ((c & 15) << 3) | (c >> 4);
        B1h[c * 256 + k] = f2bf_rne(W1[k * 128 + ch]);
    }
    if (i < 128 * 128) {               // [Wmu|Wls] -> natural transpose
        int k = i >> 7, och = i & 127;
        float vv = (och < 64) ? Wmu[k * 64 + och] : Wls[k * 64 + (och - 64)];
        B2t[och * 128 + k] = f2bf_rne(vv);
    }
}

// ---------------- CSR build: fixed-capacity bucketed (512 nodes/bucket) ----------------

// packed edge: (src << 9) | (dst & 511)
__global__ __launch_bounds__(256) void k_scatb(const int* __restrict__ srcv,
                                               const int* __restrict__ dstv,
                                               int* __restrict__ bcur,
                                               unsigned int* __restrict__ ebuf, int E) {
    __shared__ int hcnt[NBUCK_MAX], hbase[NBUCK_MAX], hcur[NBUCK_MAX];
    int t = threadIdx.x;
    for (int b = t; b < NBUCK_MAX; b += 256) { hcnt[b] = 0; hcur[b] = 0; }
    __syncthreads();
    int base = blockIdx.x * 4096;
    for (int q = 0; q < 16; ++q) {
        int i = base + q * 256 + t;
        if (i < E) atomicAdd(&hcnt[dstv[i] >> BSHIFT], 1);
    }
    __syncthreads();
    for (int b = t; b < NBUCK_MAX; b += 256)
        hbase[b] = hcnt[b] ? atomicAdd(&bcur[b], hcnt[b]) : 0;
    __syncthreads();
    for (int q = 0; q < 16; ++q) {
        int i = base + q * 256 + t;
        if (i < E) {
            int d = dstv[i], b = d >> BSHIFT;
            int off = hbase[b] + atomicAdd(&hcur[b], 1);
            if (off < BCAP)   // overflow guard (P ~ 0 for uniform dst)
                ebuf[(size_t)b * BCAP + off] = ((unsigned)srcv[i] << 9) | (unsigned)(d & 511);
        }
    }
}

// per-bucket counting sort -> colv (padded layout), rowstart/rowend, dinv
__global__ __launch_bounds__(512) void k_bsort(const unsigned int* __restrict__ ebuf,
                                               const int* __restrict__ bcur,
                                               int* __restrict__ colv,
                                               int* __restrict__ rowstart,
                                               int* __restrict__ rowend,
                                               float* __restrict__ dinv, int n) {
    __shared__ int cnt[512], sc[512], cur[512];
    int t = threadIdx.x;
    int b = blockIdx.x;
    int node0 = b << BSHIFT;
    int nn = min(512, n - node0);
    int s0 = (int)((size_t)b * BCAP);
    int total = min(bcur[b], BCAP);
    cnt[t] = 0;
    __syncthreads();
    for (int i = t; i < total; i += 512)
        atomicAdd(&cnt[ebuf[s0 + i] & 511u], 1);
    __syncthreads();
    int v = cnt[t];
    sc[t] = v;
    __syncthreads();
    for (int off = 1; off < 512; off <<= 1) {
        int x = 0;
        if (t >= off) x = sc[t - off];
        __syncthreads();
        if (t >= off) sc[t] += x;
        __syncthreads();
    }
    if (t < nn) {
        int rs = s0 + sc[t] - v;
        cur[t] = rs;
        rowstart[node0 + t] = rs;
        rowend[node0 + t] = rs + v;
        dinv[node0 + t] = rsqrtf((float)(v + 1));   // +1 self-loop
    }
    __syncthreads();
    for (int i = t; i < total; i += 512) {
        unsigned int pv = ebuf[s0 + i];
        int pos = atomicAdd(&cur[pv & 511u], 1);
        colv[pos] = (int)(pv >> 9);
    }
}

// ---------------- GEMM1: h' = fp8( F8SCALE * dinv .* (x @ W1) ) ----------------
// 16-row waves (4 waves x 16 = 64 rows/block). A row fully preloaded per lane;
// B-hi staged in LDS in two 32KB K-halves. A f32->bf16 via v_cvt_pk_bf16_f32.

__global__ __launch_bounds__(256) void k_gemm1(const float* __restrict__ A,
                                               const unsigned short* __restrict__ Bth,
                                               const float* __restrict__ dinv,
                                               unsigned char* __restrict__ Cf8, int M) {
    const int K = 256;
    __shared__ unsigned short Bs[128 * 128];   // 32 KB: one K-half
    const int tid = threadIdx.x;
    const int w = tid >> 6, l = tid & 63;
    const int lr = l & 15, lq = l >> 4;
    const int row0 = blockIdx.x * 64 + w * 16;

    int rg = row0 + lr;
    const float* ap = A + (size_t)(rg < M ? rg : 0) * K + lq * 8;

    float4 ar[8][2];
#pragma unroll
    for (int s = 0; s < 8; ++s) {
        ar[s][0] = *(const float4*)(ap + s * 32);
        ar[s][1] = *(const float4*)(ap + s * 32 + 4);
    }

    f32x4 acc[8];
#pragma unroll
    for (int ct = 0; ct < 8; ++ct) acc[ct] = (f32x4){0.f, 0.f, 0.f, 0.f};

#pragma unroll
    for (int h = 0; h < 2; ++h) {
        if (h) __syncthreads();
#pragma unroll
        for (int r = 0; r < 8; ++r) {
            int rw = r * 4 + w;
            int sl = rw >> 3, ct = rw & 7;
            short8v v = *(const short8v*)(Bth + (size_t)(ct * 16 + lr) * K + (h * 4 + sl) * 32 + lq * 8);
            *(short8v*)(&Bs[(rw * 64 + l) * 8]) = v;
        }
        __syncthreads();

#pragma unroll
        for (int sl = 0; sl < 4; ++sl) {
            int sg = h * 4 + sl;
            short8v ah = pack_bf16x8(ar[sg][0], ar[sg][1]);
#pragma unroll
            for (int ct = 0; ct < 8; ++ct) {
                short8v bh = *(const short8v*)(&Bs[((sl * 8 + ct) * 64 + l) * 8]);
                acc[ct] = __builtin_amdgcn_mfma_f32_16x16x32_bf16(ah, bh, acc[ct], 0, 0, 0);
            }
        }
    }

    int rbase = row0 + (lq << 2);
#pragma unroll
    for (int j = 0; j < 4; ++j) {
        int row = rbase + j;
        if (row < M) {
            float dv = dinv[row] * F8SCALE;
            uint2 r;
            r.x = pk_fp8(dv * acc[0][j], dv * acc[1][j], dv * acc[2][j], dv * acc[3][j]);
            r.y = pk_fp8(dv * acc[4][j], dv * acc[5][j], dv * acc[6][j], dv * acc[7][j]);
            *(uint2*)(Cf8 + (size_t)row * 128 + lr * 8) = r;
        }
    }
}

// ---------------- prop1: hidden' = fp8( F8SCALE * dinv .* relu(dinv_v*agg + b1) ) ----------------
// 4 nodes/wave, 16 lanes x 8B (fp8 row = 128B = 2 lines); unroll 4.

__global__ __launch_bounds__(256) void k_prop1(const unsigned char* __restrict__ hf,
                                               const int* __restrict__ colv,
                                               const int* __restrict__ rowstart,
                                               const int* __restrict__ rowend,
                                               const float* __restrict__ dinv,
                                               const float* __restrict__ bias,
                                               unsigned char* __restrict__ of, int n) {
    int wid = (blockIdx.x * 256 + threadIdx.x) >> 6;
    int nid = wid * 4 + ((threadIdx.x >> 4) & 3);
    if (nid >= n) return;
    int cl = threadIdx.x & 15;
    const unsigned char* hp = hf + cl * 8;
    int s = rowstart[nid], e = rowend[nid];
    float a[8] = {0.f, 0.f, 0.f, 0.f, 0.f, 0.f, 0.f, 0.f};
    int i = s;
    for (; i + 4 <= e; i += 4) {
        int c0 = colv[i], c1 = colv[i + 1], c2 = colv[i + 2], c3 = colv[i + 3];
        uint2 v0 = *(const uint2*)(hp + (size_t)c0 * 128);
        uint2 v1 = *(const uint2*)(hp + (size_t)c1 * 128);
        uint2 v2 = *(const uint2*)(hp + (size_t)c2 * 128);
        uint2 v3 = *(const uint2*)(hp + (size_t)c3 * 128);
        accf8(a, v0); accf8(a, v1); accf8(a, v2); accf8(a, v3);
    }
    for (; i < e; ++i) {
        int c = colv[i];
        uint2 v = *(const uint2*)(hp + (size_t)c * 128);
        accf8(a, v);
    }
    uint2 vo = *(const uint2*)(hp + (size_t)nid * 128);   // self-loop
    accf8(a, vo);
    float dv = dinv[nid];
    float din = dv * F8INV;          // undo x16 input scale
    float dos = dv * F8SCALE;        // re-apply for fp8 output (+ fold next-layer dinv)
    float4 b0 = *(const float4*)(bias + cl * 8);
    float4 b1v = *(const float4*)(bias + cl * 8 + 4);
    float bb[8] = {b0.x, b0.y, b0.z, b0.w, b1v.x, b1v.y, b1v.z, b1v.w};
    float o[8];
#pragma unroll
    for (int k = 0; k < 8; ++k)
        o[k] = fmaxf(a[k] * din + bb[k], 0.f) * dos;
    uint2 r;
    r.x = pk_fp8(o[0], o[1], o[2], o[3]);
    r.y = pk_fp8(o[4], o[5], o[6], o[7]);
    *(uint2*)(of + (size_t)nid * 128 + cl * 8) = r;
}

// ---------------- fused prop2 + GEMM2 + epilogue (round-15 best variant) ----------------
// Block = 16 nodes, 4 waves. Phase 1: proven 4-node/wave gather (fp8 hidden'),
// agg -> LDS bf16 [16][136] (padded, 16B-aligned rows). Phase 2: per-wave MFMA
// D = agg(16x128) @ Wtile; wave w owns och tiles {w, w+4} so mu and ls of the
// same channel land in the SAME lane -> zero-shuffle reparam, 64B-coalesced stores.

__global__ __launch_bounds__(256) void k_prop2z(const unsigned char* __restrict__ hf,
                                                const int* __restrict__ colv,
                                                const int* __restrict__ rowstart,
                                                const int* __restrict__ rowend,
                                                const float* __restrict__ dinv,
                                                const unsigned short* __restrict__ B2t,
                                                const float* __restrict__ bmu,
                                                const float* __restrict__ bls,
                                                const float* __restrict__ eps,
                                                float* __restrict__ zout,
                                                float* __restrict__ muout,
                                                float* __restrict__ lsout, int n) {
    __shared__ unsigned short aggb[16][136];   // 4.25 KB, row stride 272B (16B-aligned)
    const int tid = threadIdx.x;
    const int w = tid >> 6, l = tid & 63;
    const int base = blockIdx.x * 16;

    // ---- phase 1: gather (4 nodes/wave, 16 lanes x 8B fp8) ----
    {
        int g = l >> 4, cl = l & 15;
        int slot = w * 4 + g;
        int nid = base + slot;
        float a[8] = {0.f, 0.f, 0.f, 0.f, 0.f, 0.f, 0.f, 0.f};
        float dv = 0.f;
        if (nid < n) {
            const unsigned char* hp = hf + cl * 8;
            int s = rowstart[nid], e = rowend[nid];
            int i = s;
            for (; i + 4 <= e; i += 4) {
                int c0 = colv[i], c1 = colv[i + 1], c2 = colv[i + 2], c3 = colv[i + 3];
                uint2 v0 = *(const uint2*)(hp + (size_t)c0 * 128);
                uint2 v1 = *(const uint2*)(hp + (size_t)c1 * 128);
                uint2 v2 = *(const uint2*)(hp + (size_t)c2 * 128);
                uint2 v3 = *(const uint2*)(hp + (size_t)c3 * 128);
                accf8(a, v0); accf8(a, v1); accf8(a, v2); accf8(a, v3);
            }
            for (; i < e; ++i) {
                int c = colv[i];
                uint2 v = *(const uint2*)(hp + (size_t)c * 128);
                accf8(a, v);
            }
            uint2 vo = *(const uint2*)(hp + (size_t)nid * 128);   // self-loop
            accf8(a, vo);
            dv = dinv[nid] * F8INV;
        }
        short8v r;
#pragma unroll
        for (int k = 0; k < 8; ++k) r[k] = (short)f2bf_rne(a[k] * dv);
        *(short8v*)(&aggb[slot][cl * 8]) = r;
    }
    __syncthreads();

    // ---- phase 2: MFMA. A = agg (rows = nodes, from LDS); B = W tile (cols = och, from L2).
    const int lr = l & 15, lq = l >> 4;
    f32x4 acc0 = (f32x4){0.f, 0.f, 0.f, 0.f};
    f32x4 acc1 = (f32x4){0.f, 0.f, 0.f, 0.f};
#pragma unroll
    for (int sl = 0; sl < 4; ++sl) {
        short8v af = *(const short8v*)(&aggb[lr][sl * 32 + lq * 8]);
        short8v b0 = *(const short8v*)(B2t + (size_t)(w * 16 + lr) * 128 + sl * 32 + lq * 8);
        short8v b1 = *(const short8v*)(B2t + (size_t)((w + 4) * 16 + lr) * 128 + sl * 32 + lq * 8);
        acc0 = __builtin_amdgcn_mfma_f32_16x16x32_bf16(af, b0, acc0, 0, 0, 0);
        acc1 = __builtin_amdgcn_mfma_f32_16x16x32_bf16(af, b1, acc1, 0, 0, 0);
    }

    // ---- epilogue: D col (lane&15) = och-in-tile; row (lq*4+j) = node slot ----
    int och = w * 16 + lr;             // mu channel; ls channel is the same offset
    float bmv = bmu[och], blv = bls[och];
#pragma unroll
    for (int j = 0; j < 4; ++j) {
        int nid = base + lq * 4 + j;
        if (nid < n) {
            float mu = acc0[j] + bmv;
            float ls = acc1[j] + blv;
            size_t o = (size_t)nid * 64 + och;
            float z = mu + eps[o] * __expf(ls);
            zout[o] = z;
            muout[o] = mu;
            lsout[o] = ls;
        }
    }
}

// ---------------- launch ----------------

extern "C" void kernel_launch(void* const* d_in, const int* in_sizes, int n_in,
                              void* d_out, int out_size, void* d_ws, size_t ws_size,
                              hipStream_t stream) {
    const float* x   = (const float*)d_in[0];
    const int*   ei  = (const int*)d_in[1];
    const float* W1  = (const float*)d_in[2];
    const float* b1  = (const float*)d_in[3];
    const float* Wmu = (const float*)d_in[4];
    const float* bmu = (const float*)d_in[5];
    const float* Wls = (const float*)d_in[6];
    const float* bls = (const float*)d_in[7];
    const float* eps = (const float*)d_in[8];

    const int n = in_sizes[0] / 256;   // 100000
    const int E = in_sizes[1] / 2;     // 1600000
    const int* srcv = ei;
    const int* dstv = ei + E;
    const int nbuck = (n + 511) >> BSHIFT;

    char* w = (char*)d_ws;
    auto alloc = [&](size_t bytes) -> char* {
        char* p = w;
        w += (bytes + 255) & ~(size_t)255;
        return p;
    };
    float* dinv     = (float*)alloc((size_t)n * 4);
    int*   rowstart = (int*)alloc((size_t)n * 4);
    int*   rowend   = (int*)alloc((size_t)n * 4);
    int*   bcur     = (int*)alloc((size_t)NBUCK_MAX * 4);
    unsigned int* ebuf = (unsigned int*)alloc((size_t)nbuck * BCAP * 4);
    int*   colv     = (int*)alloc((size_t)nbuck * BCAP * 4);
    unsigned short* B1h = (unsigned short*)alloc(128 * 256 * 2);
    unsigned short* B2t = (unsigned short*)alloc(128 * 128 * 2);
    unsigned char* hf8   = (unsigned char*)alloc((size_t)n * 128);   // h' fp8
    unsigned char* hidf8 = (unsigned char*)alloc((size_t)n * 128);   // hidden' fp8

    const int ecb = (E + 4095) / 4096;

    k_prepB<<<128, 256, 0, stream>>>(W1, Wmu, Wls, B1h, B2t, bcur);
    k_scatb<<<ecb, 256, 0, stream>>>(srcv, dstv, bcur, ebuf, E);
    k_bsort<<<nbuck, 512, 0, stream>>>(ebuf, bcur, colv, rowstart, rowend, dinv, n);

    k_gemm1<<<(n + 63) / 64, 256, 0, stream>>>(x, B1h, dinv, hf8, n);
    k_prop1<<<(n + 15) / 16, 256, 0, stream>>>(hf8, colv, rowstart, rowend, dinv, b1, hidf8, n);

    float* zout  = (float*)d_out;
    float* muout = zout + (size_t)n * 64;
    float* lsout = muout + (size_t)n * 64;
    k_prop2z<<<(n + 15) / 16, 256, 0, stream>>>(hidf8, colv, rowstart, rowend, dinv,
                                                B2t, bmu, bls, eps,
                                                zout, muout, lsout, n);
}